// Round 1
// baseline (1815.086 us; speedup 1.0000x reference)
//
#include <hip/hip_runtime.h>
#include <stdint.h>

#define Bz 4
#define Sz 1024
#define DIMz 4096
#define Hz 32
#define HDz 128
#define ALz 10

typedef unsigned short u16;
typedef __attribute__((ext_vector_type(8))) short short8;
typedef __attribute__((ext_vector_type(4))) float fx4;

__device__ __forceinline__ u16 f2b(float f){
  union { float f; unsigned u; } v; v.f = f;
  unsigned r = v.u + 0x7FFFu + ((v.u >> 16) & 1u);
  return (u16)(r >> 16);
}
__device__ __forceinline__ float b2f(u16 h){
  union { unsigned u; float f; } v; v.u = ((unsigned)h) << 16; return v.f;
}
__device__ __forceinline__ void gload16(const void* g, void* l){
  __builtin_amdgcn_global_load_lds(
    (const __attribute__((address_space(1))) uint32_t*)g,
    (__attribute__((address_space(3))) uint32_t*)l, 16, 0, 0);
}

// ---------- conversions ----------
// generic f32 -> bf16 with row zero-padding (dstRows >= srcRows)
__global__ void k_f2b_pad(const float* __restrict__ src, u16* __restrict__ dst,
                          int srcRows, int cols, int dstRows){
  size_t i = (size_t)blockIdx.x * 1024 + (size_t)threadIdx.x * 4;
  int row = (int)(i / cols);
  if (row < srcRows){
    fx4 v = *(const fx4*)(src + i);
    dst[i] = f2b(v[0]); dst[i+1] = f2b(v[1]); dst[i+2] = f2b(v[2]); dst[i+3] = f2b(v[3]);
  } else {
    dst[i] = 0; dst[i+1] = 0; dst[i+2] = 0; dst[i+3] = 0;
  }
}

// Xcat: rows 0..4095 = x (B*S,DIM); 4096..4135 = adapter (40,DIM); rest 0
__global__ void k_xcat(const float* __restrict__ x, const float* __restrict__ ad,
                       u16* __restrict__ dst){
  size_t i = (size_t)blockIdx.x * 1024 + (size_t)threadIdx.x * 4;
  int row = (int)(i >> 12);
  int col = (int)(i & 4095);
  const float* s = nullptr;
  if (row < 4096) s = x + i;
  else if (row < 4096 + Bz*ALz) s = ad + (size_t)(row - 4096) * DIMz + col;
  if (s){
    fx4 v = *(const fx4*)s;
    dst[i] = f2b(v[0]); dst[i+1] = f2b(v[1]); dst[i+2] = f2b(v[2]); dst[i+3] = f2b(v[3]);
  } else {
    dst[i] = 0; dst[i+1] = 0; dst[i+2] = 0; dst[i+3] = 0;
  }
}

// concat lora l1 weights: rows 0..15=q, 16..31=k, 32..47=v, rest 0  (128x4096 bf16)
__global__ void k_l1cat(const float* __restrict__ a, const float* __restrict__ b,
                        const float* __restrict__ c, u16* __restrict__ dst){
  size_t i = (size_t)blockIdx.x * 1024 + (size_t)threadIdx.x * 4;
  int row = (int)(i >> 12);
  int col = (int)(i & 4095);
  const float* s = nullptr;
  if (row < 16) s = a + (size_t)row * 4096 + col;
  else if (row < 32) s = b + (size_t)(row - 16) * 4096 + col;
  else if (row < 48) s = c + (size_t)(row - 32) * 4096 + col;
  if (s){
    fx4 v = *(const fx4*)s;
    dst[i] = f2b(v[0]); dst[i+1] = f2b(v[1]); dst[i+2] = f2b(v[2]); dst[i+3] = f2b(v[3]);
  } else {
    dst[i] = 0; dst[i+1] = 0; dst[i+2] = 0; dst[i+3] = 0;
  }
}

// ---------- NT bf16 GEMM: C[m][n] = sum_k A[m][k]*B[n][k] ----------
// 128x128 tile, BK=64, 256 threads (4 waves, each 64x64), global_load_lds staging.
__global__ __launch_bounds__(256)
void gemm_nt(const u16* __restrict__ A, const u16* __restrict__ Bm, void* __restrict__ Cp,
             int M, int N, int K, int outBf16){
  __shared__ __align__(16) u16 As[128][64];
  __shared__ __align__(16) u16 Bs[128][64];
  const int tid = threadIdx.x;
  const int w = tid >> 6, l = tid & 63;
  const int lrow = l & 15, lgrp = l >> 4;
  const int bm = blockIdx.y * 128, bn = blockIdx.x * 128;
  const int wr = (w >> 1) * 64, wc = (w & 1) * 64;

  const fx4 fz = {0.f, 0.f, 0.f, 0.f};
  fx4 acc[4][4];
#pragma unroll
  for (int i = 0; i < 4; i++)
#pragma unroll
    for (int j = 0; j < 4; j++) acc[i][j] = fz;

  const u16* Abase = A + (size_t)bm * K;
  const u16* Bbase = Bm + (size_t)bn * K;

  for (int k0 = 0; k0 < K; k0 += 64){
    __syncthreads();
#pragma unroll
    for (int i = 0; i < 4; i++){
      int c = i * 256 + tid;
      int row = c >> 3, off = (c & 7) << 3;
      gload16(Abase + (size_t)row * K + k0 + off, ((u16*)As) + c * 8);
      gload16(Bbase + (size_t)row * K + k0 + off, ((u16*)Bs) + c * 8);
    }
    __syncthreads();
#pragma unroll
    for (int kk = 0; kk < 2; kk++){
      short8 a[4], b[4];
#pragma unroll
      for (int i = 0; i < 4; i++) a[i] = *(const short8*)&As[wr + i*16 + lrow][kk*32 + lgrp*8];
#pragma unroll
      for (int j = 0; j < 4; j++) b[j] = *(const short8*)&Bs[wc + j*16 + lrow][kk*32 + lgrp*8];
#pragma unroll
      for (int i = 0; i < 4; i++)
#pragma unroll
        for (int j = 0; j < 4; j++)
          acc[i][j] = __builtin_amdgcn_mfma_f32_16x16x32_bf16(a[i], b[j], acc[i][j], 0, 0, 0);
    }
  }

  if (outBf16){
    u16* C = (u16*)Cp;
#pragma unroll
    for (int i = 0; i < 4; i++)
#pragma unroll
      for (int r = 0; r < 4; r++){
        int gm = bm + wr + i*16 + lgrp*4 + r;
        u16* crow = C + (size_t)gm * N + bn + wc + lrow;
#pragma unroll
        for (int j = 0; j < 4; j++) crow[j*16] = f2b(acc[i][j][r]);
      }
  } else {
    float* C = (float*)Cp;
#pragma unroll
    for (int i = 0; i < 4; i++)
#pragma unroll
      for (int r = 0; r < 4; r++){
        int gm = bm + wr + i*16 + lgrp*4 + r;
        float* crow = C + (size_t)gm * N + bn + wc + lrow;
#pragma unroll
        for (int j = 0; j < 4; j++) crow[j*16] = acc[i][j][r];
      }
  }
}

// ---------- LoRA rank-16 add:  y[m][o] += dot(t[m][roff..roff+16], l2[o][0..16]) ----------
__global__ void k_lora_add_b(u16* __restrict__ y, const float* __restrict__ t,
                             const float* __restrict__ l2, int roff){
  int o = blockIdx.x * 256 + threadIdx.x;
  int m = blockIdx.y;
  const fx4* tv = (const fx4*)(t + (size_t)m * 128 + roff);
  const fx4* lv = (const fx4*)(l2 + (size_t)o * 16);
  float s = 0.f;
#pragma unroll
  for (int r = 0; r < 4; r++){
    fx4 a = tv[r], b = lv[r];
    s += a[0]*b[0] + a[1]*b[1] + a[2]*b[2] + a[3]*b[3];
  }
  size_t idx = (size_t)m * DIMz + o;
  y[idx] = f2b(b2f(y[idx]) + s);
}

__global__ void k_lora_add_f(float* __restrict__ y, const float* __restrict__ t,
                             const float* __restrict__ l2, int roff){
  int o = blockIdx.x * 256 + threadIdx.x;
  int m = blockIdx.y;
  const fx4* tv = (const fx4*)(t + (size_t)m * 128 + roff);
  const fx4* lv = (const fx4*)(l2 + (size_t)o * 16);
  float s = 0.f;
#pragma unroll
  for (int r = 0; r < 4; r++){
    fx4 a = tv[r], b = lv[r];
    s += a[0]*b[0] + a[1]*b[1] + a[2]*b[2] + a[3]*b[3];
  }
  y[(size_t)m * DIMz + o] += s;
}

// ---------- RoPE + (B,S,DIM)->(B,H,S,HD) ----------
__global__ void k_rope(const u16* __restrict__ x, u16* __restrict__ out,
                       const float* __restrict__ fcos, const float* __restrict__ fsin){
  int m = blockIdx.x;              // 0..B*S-1
  int b = m >> 10, s = m & 1023;
#pragma unroll
  for (int i = 0; i < 8; i++){
    int p = i * 256 + threadIdx.x; // 0..2047
    int h = p >> 6, j = p & 63;
    size_t xi = (size_t)m * DIMz + h * HDz + 2 * j;
    float r = b2f(x[xi]), im = b2f(x[xi + 1]);
    float c = fcos[s * 64 + j], sn = fsin[s * 64 + j];
    size_t oi = (((size_t)b * Hz + h) * Sz + s) * HDz + 2 * j;
    out[oi]     = f2b(r * c - im * sn);
    out[oi + 1] = f2b(r * sn + im * c);
  }
}

// ---------- V: (B,S,H,HD) -> Vt (B,H,HD,S) ----------
__global__ void k_vtrans(const u16* __restrict__ x, u16* __restrict__ vt){
  __shared__ __align__(16) u16 tile[64][128];
  int bh = blockIdx.y;
  int b = bh >> 5, h = bh & 31;
  int s0 = blockIdx.x * 64;
  int tid = threadIdx.x;
#pragma unroll
  for (int i = 0; i < 4; i++){
    int c = i * 256 + tid;           // 0..1023
    int ss = c >> 4, d8 = (c & 15) << 3;
    *(short8*)&tile[ss][d8] =
      *(const short8*)&x[(size_t)(b * Sz + s0 + ss) * DIMz + h * HDz + d8];
  }
  __syncthreads();
#pragma unroll
  for (int i = 0; i < 4; i++){
    int c = i * 256 + tid;
    int d = c >> 3, s8 = (c & 7) << 3;
    short8 v;
#pragma unroll
    for (int k = 0; k < 8; k++) v[k] = (short)tile[s8 + k][d];
    *(short8*)&vt[((size_t)bh * HDz + d) * Sz + s0 + s8] = v;
  }
}

// ---------- adapter K/V reshape: rows of xk/xv at offset 4096 -> AK (B,H,16,HD), AVt (B,H,HD,32) ----------
__global__ void k_adresh(const u16* __restrict__ akf, const u16* __restrict__ avf,
                         u16* __restrict__ AK, u16* __restrict__ AVt){
  int bh = blockIdx.x;
  int b = bh >> 5, h = bh & 31;
  int tid = threadIdx.x;
#pragma unroll
  for (int i = 0; i < 8; i++){
    int e = i * 256 + tid;           // 0..2047
    int jj = e >> 7, d = e & 127;
    u16 v = (jj < ALz) ? akf[(size_t)(b * ALz + jj) * DIMz + h * HDz + d] : (u16)0;
    AK[((size_t)bh * 16 + jj) * HDz + d] = v;
  }
#pragma unroll
  for (int i = 0; i < 16; i++){
    int e = i * 256 + tid;           // 0..4095
    int d = e >> 5, jj = e & 31;
    u16 v = (jj < ALz) ? avf[(size_t)(b * ALz + jj) * DIMz + h * HDz + d] : (u16)0;
    AVt[((size_t)bh * HDz + d) * 32 + jj] = v;
  }
}

// ---------- flash attention + gated adapter attention ----------
__global__ __launch_bounds__(256)
void k_attn(const u16* __restrict__ Q, const u16* __restrict__ Kg,
            const u16* __restrict__ Vt, const u16* __restrict__ AKg,
            const u16* __restrict__ AVg, const float* __restrict__ gate,
            u16* __restrict__ outp){
  __shared__ __align__(16) u16 Qs[64][128];
  __shared__ __align__(16) u16 Ks[64][128];
  __shared__ __align__(16) u16 Vs[128][64];
  __shared__ __align__(16) u16 AKs[16][128];
  __shared__ __align__(16) u16 AVs[128][32];
  __shared__ __align__(16) u16 Ps[4][16][64];

  const int bh = blockIdx.y;
  const int b = bh >> 5, h = bh & 31;
  const int q0 = blockIdx.x * 64;
  const int tid = threadIdx.x;
  const int w = tid >> 6, l = tid & 63;
  const int lrow = l & 15, lgrp = l >> 4;

  const u16* Qb = Q  + (size_t)bh * (Sz * HDz) + (size_t)q0 * HDz;
  const u16* Kb = Kg + (size_t)bh * (Sz * HDz);
  const u16* Vb = Vt + (size_t)bh * (HDz * Sz);

#pragma unroll
  for (int i = 0; i < 4; i++){
    int c = i * 256 + tid;
    gload16(Qb + c * 8, ((u16*)Qs) + c * 8);
  }
  gload16(AKg + (size_t)bh * (16 * HDz) + tid * 8, ((u16*)AKs) + tid * 8);
#pragma unroll
  for (int i = 0; i < 2; i++){
    int c = i * 256 + tid;
    gload16(AVg + (size_t)bh * (HDz * 32) + c * 8, ((u16*)AVs) + c * 8);
  }
  __syncthreads();

  const fx4 fz = {0.f, 0.f, 0.f, 0.f};
  fx4 o[8];
#pragma unroll
  for (int i = 0; i < 8; i++) o[i] = fz;
  float mrow[4], lsum[4];
#pragma unroll
  for (int r = 0; r < 4; r++){ mrow[r] = -1e30f; lsum[r] = 0.f; }

  const float scale = 0.088388347648318447f; // 1/sqrt(128)
  const int qrowbase = q0 + w * 16 + lgrp * 4;
  const int ktiles = blockIdx.x + 1;

  for (int kt = 0; kt < ktiles; kt++){
    const int k0 = kt * 64;
    __syncthreads();
#pragma unroll
    for (int i = 0; i < 4; i++){
      int c = i * 256 + tid;
      gload16(Kb + (size_t)k0 * HDz + c * 8, ((u16*)Ks) + c * 8);
    }
#pragma unroll
    for (int i = 0; i < 4; i++){
      int c = i * 256 + tid;
      int d = c >> 3, off = (c & 7) << 3;
      gload16(Vb + (size_t)d * Sz + k0 + off, ((u16*)Vs) + c * 8);
    }
    __syncthreads();

    // QK^T
    fx4 sc[4];
#pragma unroll
    for (int j = 0; j < 4; j++) sc[j] = fz;
#pragma unroll
    for (int kk = 0; kk < 4; kk++){
      short8 aq = *(const short8*)&Qs[w*16 + lrow][kk*32 + lgrp*8];
#pragma unroll
      for (int j = 0; j < 4; j++){
        short8 bk = *(const short8*)&Ks[j*16 + lrow][kk*32 + lgrp*8];
        sc[j] = __builtin_amdgcn_mfma_f32_16x16x32_bf16(aq, bk, sc[j], 0, 0, 0);
      }
    }
    const int last = (kt == ktiles - 1);
    float tm[4];
#pragma unroll
    for (int r = 0; r < 4; r++){
      float mx = -1e30f;
#pragma unroll
      for (int j = 0; j < 4; j++){
        float v = sc[j][r] * scale;
        if (last){
          int kcol = k0 + j*16 + lrow;
          if (kcol > qrowbase + r) v = -1e30f;
        }
        sc[j][r] = v;
        mx = fmaxf(mx, v);
      }
#pragma unroll
      for (int d = 1; d < 16; d <<= 1) mx = fmaxf(mx, __shfl_xor(mx, d));
      tm[r] = mx;
    }
    float esc[4];
#pragma unroll
    for (int r = 0; r < 4; r++){
      float nm = fmaxf(mrow[r], tm[r]);
      esc[r] = __expf(mrow[r] - nm);
      mrow[r] = nm;
      float s = 0.f;
#pragma unroll
      for (int j = 0; j < 4; j++){
        float p = __expf(sc[j][r] - nm);
        sc[j][r] = p;
        s += p;
      }
#pragma unroll
      for (int d = 1; d < 16; d <<= 1) s += __shfl_xor(s, d);
      lsum[r] = lsum[r] * esc[r] + s;
    }
#pragma unroll
    for (int j = 0; j < 8; j++)
#pragma unroll
      for (int r = 0; r < 4; r++) o[j][r] *= esc[r];
    // P -> LDS (per-wave region)
#pragma unroll
    for (int j = 0; j < 4; j++)
#pragma unroll
      for (int r = 0; r < 4; r++)
        Ps[w][lgrp*4 + r][j*16 + lrow] = f2b(sc[j][r]);
    // PV
#pragma unroll
    for (int kk = 0; kk < 2; kk++){
      short8 ap = *(const short8*)&Ps[w][lrow][kk*32 + lgrp*8];
#pragma unroll
      for (int j = 0; j < 8; j++){
        short8 bv = *(const short8*)&Vs[j*16 + lrow][kk*32 + lgrp*8];
        o[j] = __builtin_amdgcn_mfma_f32_16x16x32_bf16(ap, bv, o[j], 0, 0, 0);
      }
    }
  }

  // normalize main attention
#pragma unroll
  for (int j = 0; j < 8; j++)
#pragma unroll
    for (int r = 0; r < 4; r++) o[j][r] /= lsum[r];

  // adapter attention (separate softmax, tanh(gate) scaling)
  fx4 s2 = fz;
#pragma unroll
  for (int kk = 0; kk < 4; kk++){
    short8 aq = *(const short8*)&Qs[w*16 + lrow][kk*32 + lgrp*8];
    short8 bk = *(const short8*)&AKs[lrow][kk*32 + lgrp*8];
    s2 = __builtin_amdgcn_mfma_f32_16x16x32_bf16(aq, bk, s2, 0, 0, 0);
  }
  const float g = tanhf(gate[h]);
#pragma unroll
  for (int r = 0; r < 4; r++){
    float v = s2[r] * scale;
    if (lrow >= ALz) v = -1e30f;
    float mx = v;
#pragma unroll
    for (int d = 1; d < 16; d <<= 1) mx = fmaxf(mx, __shfl_xor(mx, d));
    float p = __expf(v - mx);
    float s = p;
#pragma unroll
    for (int d = 1; d < 16; d <<= 1) s += __shfl_xor(s, d);
    float p2 = g * p / s;
    Ps[w][lgrp*4 + r][lrow] = f2b(p2);
    Ps[w][lgrp*4 + r][16 + lrow] = 0;
  }
  {
    short8 ap = *(const short8*)&Ps[w][lrow][lgrp*8];
#pragma unroll
    for (int j = 0; j < 8; j++){
      short8 bv = *(const short8*)&AVs[j*16 + lrow][lgrp*8];
      o[j] = __builtin_amdgcn_mfma_f32_16x16x32_bf16(ap, bv, o[j], 0, 0, 0);
    }
  }

  // write (B,S,H*HD) bf16
  u16* ob = outp + (size_t)(b * Sz + q0) * DIMz + h * HDz;
#pragma unroll
  for (int j = 0; j < 8; j++)
#pragma unroll
    for (int r = 0; r < 4; r++){
      int row = w*16 + lgrp*4 + r;
      ob[(size_t)row * DIMz + j*16 + lrow] = f2b(o[j][r]);
    }
}

// ---------- host ----------
extern "C" void kernel_launch(void* const* d_in, const int* in_sizes, int n_in,
                              void* d_out, int out_size, void* d_ws, size_t ws_size,
                              hipStream_t stream){
  const float* x    = (const float*)d_in[0];
  const float* adap = (const float*)d_in[1];
  const float* wq   = (const float*)d_in[2];
  const float* wk   = (const float*)d_in[3];
  const float* wv   = (const float*)d_in[4];
  const float* wo   = (const float*)d_in[5];
  const float* lq1  = (const float*)d_in[6];
  const float* lq2  = (const float*)d_in[7];
  const float* lk1  = (const float*)d_in[8];
  const float* lk2  = (const float*)d_in[9];
  const float* lv1  = (const float*)d_in[10];
  const float* lv2  = (const float*)d_in[11];
  const float* lo1  = (const float*)d_in[12];
  const float* lo2  = (const float*)d_in[13];
  const float* gate = (const float*)d_in[14];
  const float* fcos = (const float*)d_in[15];
  const float* fsin = (const float*)d_in[16];
  // mask (d_in[17]) and start_pos (d_in[18]) are implicit (causal, 0)

  const size_t MB = 1024 * 1024;
  char* ws = (char*)d_ws;
  u16*  Xcat = (u16*)(ws);                       // 4224x4096 bf16 (33 MB);  later Q (B,H,S,HD)
  u16*  Wb   = (u16*)(ws + 33 * MB);             // 4096x4096 bf16 (32 MB);  later K (B,H,S,HD)
  u16*  xq   = (u16*)(ws + 65 * MB);             // 4224x4096 bf16 (33 MB);  later attn_out
  u16*  xk   = (u16*)(ws + 98 * MB);             // 33 MB
  u16*  xv   = (u16*)(ws + 131 * MB);            // 33 MB
  u16*  Vt   = (u16*)(ws + 164 * MB);            // (B,H,HD,S) bf16 (32 MB)
  u16*  l1b  = (u16*)(ws + 196 * MB);            // 128x4096 bf16 (1 MB)
  float* t   = (float*)(ws + 197 * MB);          // 4224x128 f32 (2.0625 MB)
  u16*  AKb  = (u16*)(ws + 200 * MB);            // (B,H,16,HD) bf16 (0.5 MB)
  u16*  AVb  = (u16*)(ws + 201 * MB);            // (B,H,HD,32) bf16 (1 MB)
  u16*  Qb = Xcat;
  u16*  Kb = Wb;
  u16*  attn = xq;
  float* out = (float*)d_out;

  dim3 blk(256);
  const int MCAT = 4224; // 4096 + 40 adapter rows + pad to x128

  // X||adapter -> bf16
  k_xcat<<<dim3(MCAT * 4096 / 1024), blk, 0, stream>>>(x, adap, Xcat);

  // Q/K/V projections (adapter rows ride along in K/V gemms)
  k_f2b_pad<<<dim3(4096 * 4096 / 1024), blk, 0, stream>>>(wq, Wb, 4096, 4096, 4096);
  gemm_nt<<<dim3(32, 33), blk, 0, stream>>>(Xcat, Wb, xq, MCAT, 4096, 4096, 1);
  k_f2b_pad<<<dim3(4096 * 4096 / 1024), blk, 0, stream>>>(wk, Wb, 4096, 4096, 4096);
  gemm_nt<<<dim3(32, 33), blk, 0, stream>>>(Xcat, Wb, xk, MCAT, 4096, 4096, 1);
  k_f2b_pad<<<dim3(4096 * 4096 / 1024), blk, 0, stream>>>(wv, Wb, 4096, 4096, 4096);
  gemm_nt<<<dim3(32, 33), blk, 0, stream>>>(Xcat, Wb, xv, MCAT, 4096, 4096, 1);

  // LoRA l1 (q,k,v concatenated) then rank-16 adds
  k_l1cat<<<dim3(128 * 4096 / 1024), blk, 0, stream>>>(lq1, lk1, lv1, l1b);
  gemm_nt<<<dim3(1, 33), blk, 0, stream>>>(Xcat, l1b, t, MCAT, 128, 4096, 0);
  k_lora_add_b<<<dim3(16, 4096), blk, 0, stream>>>(xq, t, lq2, 0);
  k_lora_add_b<<<dim3(16, 4096), blk, 0, stream>>>(xk, t, lk2, 16);
  k_lora_add_b<<<dim3(16, 4096), blk, 0, stream>>>(xv, t, lv2, 32);

  // RoPE / reshape (Xcat and Wb are dead as GEMM operands now)
  k_rope<<<dim3(4096), blk, 0, stream>>>(xq, Qb, fcos, fsin);
  k_rope<<<dim3(4096), blk, 0, stream>>>(xk, Kb, fcos, fsin);
  k_vtrans<<<dim3(16, 128), blk, 0, stream>>>(xv, Vt);
  k_adresh<<<dim3(128), blk, 0, stream>>>(xk + (size_t)4096 * 4096,
                                          xv + (size_t)4096 * 4096, AKb, AVb);

  // attention
  k_attn<<<dim3(16, 128), blk, 0, stream>>>(Qb, Kb, Vt, AKb, AVb, gate, attn);

  // output projection + LoRA
  k_f2b_pad<<<dim3(4096 * 4096 / 1024), blk, 0, stream>>>(wo, Wb, 4096, 4096, 4096);
  gemm_nt<<<dim3(32, 32), blk, 0, stream>>>(attn, Wb, out, 4096, 4096, 4096, 0);
  k_f2b_pad<<<dim3(128 * 4096 / 1024), blk, 0, stream>>>(lo1, l1b, 16, 4096, 128);
  gemm_nt<<<dim3(1, 32), blk, 0, stream>>>(attn, l1b, t, 4096, 128, 4096, 0);
  k_lora_add_f<<<dim3(16, 4096), blk, 0, stream>>>(out, t, lo2, 0);
}